// Round 7
// baseline (766.422 us; speedup 1.0000x reference)
//
#include <hip/hip_runtime.h>

#define N_NODES  100000
#define N_EDGES  1600000
#define N_GRAPHS 512
#define LN_EPS   1e-5f

#define NB    256          // dst buckets
#define NPB   391          // nodes per bucket (256*391 = 100096 >= N_NODES)
#define BCAP  8192         // pool capacity per bucket
#define PCHUNK 8192
#define PBLOCKS ((N_EDGES + PCHUNK - 1) / PCHUNK)   // 196
#define POOL_CHUNK 64
#define POOL_BLOCKS ((N_NODES + POOL_CHUNK - 1) / POOL_CHUNK)  // 1563

typedef unsigned short u16;
typedef unsigned int   u32;
typedef __attribute__((ext_vector_type(8))) short bf16x8;
typedef __attribute__((ext_vector_type(4))) float f32x4;

__device__ __forceinline__ float b2f(u16 v) {
    u32 u = ((u32)v) << 16;
    return __builtin_bit_cast(float, u);
}
__device__ __forceinline__ u16 f2b(float f) {
    u32 u = __builtin_bit_cast(u32, f);
    u32 r = (u + 0x7fffu + ((u >> 16) & 1u)) >> 16;  // RNE
    return (u16)r;
}

// ---------------- bucketed CSR build ----------------

__global__ __launch_bounds__(256)
void partition_edges(const int* __restrict__ src, const int* __restrict__ dst,
                     int* __restrict__ bcnt, uint2* __restrict__ bpool) {
    __shared__ int hist[NB];
    __shared__ int gbase[NB];
    __shared__ int cur[NB];
    int t = threadIdx.x;
    int e0 = blockIdx.x * PCHUNK;
    int e1 = e0 + PCHUNK; if (e1 > N_EDGES) e1 = N_EDGES;

    hist[t] = 0;
    __syncthreads();
    for (int e = e0 + t; e < e1; e += 256)
        atomicAdd(&hist[dst[e] / NPB], 1);
    __syncthreads();
    int h = hist[t];
    gbase[t] = (h > 0) ? atomicAdd(&bcnt[t], h) : 0;
    cur[t] = 0;
    __syncthreads();
    for (int e = e0 + t; e < e1; e += 256) {
        int d = dst[e], s = src[e];
        int b = d / NPB;
        int p = atomicAdd(&cur[b], 1);
        bpool[(size_t)b * BCAP + gbase[b] + p] = make_uint2((u32)d, (u32)s);
    }
}

__global__ void scan_buckets(const int* __restrict__ bcnt, int* __restrict__ bbase,
                             int* __restrict__ offsets) {
    __shared__ int sh[NB];
    int t = threadIdx.x;
    int v = bcnt[t];
    sh[t] = v; __syncthreads();
    for (int off = 1; off < NB; off <<= 1) {
        int add = (t >= off) ? sh[t - off] : 0;
        __syncthreads();
        sh[t] += add;
        __syncthreads();
    }
    bbase[t] = sh[t] - v;                         // exclusive
    if (t == NB - 1) offsets[N_NODES] = sh[t];    // == N_EDGES
}

__global__ __launch_bounds__(256)
void build_csr_bucket(const int* __restrict__ bcnt, const int* __restrict__ bbase,
                      const uint2* __restrict__ bpool,
                      int* __restrict__ offsets, int* __restrict__ csr) {
    __shared__ int sA[512];
    __shared__ int sB[512];
    __shared__ int csrL[BCAP];
    int b = blockIdx.x, t = threadIdx.x;
    int nlo = b * NPB;
    int NL = N_NODES - nlo; if (NL > NPB) NL = NPB;
    int count = bcnt[b], base = bbase[b];
    const uint2* pool = bpool + (size_t)b * BCAP;

    sA[t] = 0; sA[t + 256] = 0;
    __syncthreads();
    for (int i = t; i < count; i += 256)
        atomicAdd(&sA[(int)pool[i].x - nlo], 1);
    __syncthreads();
    int c0 = sA[t], c1 = sA[t + 256];

    int* a = sA; int* c = sB;
    for (int off = 1; off < 512; off <<= 1) {
        c[t]       = a[t]       + ((t >= off)       ? a[t - off]       : 0);
        c[t + 256] = a[t + 256] + ((t + 256 >= off) ? a[t + 256 - off] : 0);
        __syncthreads();
        int* tmp = a; a = c; c = tmp;
    }
    int ex0 = a[t] - c0, ex1 = a[t + 256] - c1;   // exclusive
    if (t < NL)       offsets[nlo + t]       = base + ex0;
    if (t + 256 < NL) offsets[nlo + t + 256] = base + ex1;
    c[t] = ex0; c[t + 256] = ex1;
    __syncthreads();
    for (int i = t; i < count; i += 256) {
        uint2 p = pool[i];
        int pos = atomicAdd(&c[(int)p.x - nlo], 1);
        csrL[pos] = (int)p.y;
    }
    __syncthreads();
    for (int i = t; i < count; i += 256)
        csr[base + i] = csrL[i];
}

// ---------------- dtype conversions ----------------

__global__ __launch_bounds__(256)
void conv_f32_bf16(const float* __restrict__ in, u16* __restrict__ out, int n4) {
    int i = blockIdx.x * 256 + threadIdx.x;
    if (i < n4) {
        float4 v = ((const float4*)in)[i];
        u32 lo = (u32)f2b(v.x) | ((u32)f2b(v.y) << 16);
        u32 hi = (u32)f2b(v.z) | ((u32)f2b(v.w) << 16);
        ((uint2*)out)[i] = make_uint2(lo, hi);
    }
}

__global__ __launch_bounds__(256)
void conv_weights(const float* __restrict__ Wl, const float* __restrict__ Wr,
                  int K1, int KC, u16* __restrict__ Wt) {
    int idx = blockIdx.x * 256 + threadIdx.x;
    if (idx >= 128 * KC) return;
    int c = idx / KC, k = idx % KC;
    float v = (k < K1) ? Wl[k * 128 + c] : Wr[(k - K1) * 128 + c];
    Wt[idx] = f2b(v);
}

// ---------------- mean aggregation: XCD channel-sliced gather ----------------
// ROWU32 = row length in u32 (64 for 128ch, 32 for 64ch). SLICES slices of
// 8 u32 (16 ch, 3.2 MB) each. slice = blockIdx & (SLICES-1): dispatcher
// round-robins blocks over 8 XCDs, so a slice's 3.2 MB working set stays
// resident in one XCD's 4MB L2 -> gathers become L2 hits. csr stream and
// output stores are NON-TEMPORAL so they don't evict the feature slice.
// 8 lanes per node (32 B slice), 32 nodes per 256-thr block, 4-way unroll.

template<int ROWU32, int SLICES>
__global__ __launch_bounds__(256)
void aggregate_slice(const u16* __restrict__ in, const int* __restrict__ offsets,
                     const int* __restrict__ csr, u16* __restrict__ out) {
    int slice = blockIdx.x & (SLICES - 1);
    int chunk = blockIdx.x / SLICES;
    int grp = threadIdx.x >> 3;          // node within block (0..31)
    int sub = threadIdx.x & 7;           // u32 within slice
    int n = chunk * 32 + grp;            // 3125*32 == N_NODES exact
    int o0 = offsets[n], o1 = offsets[n + 1];
    int deg = o1 - o0;
    float inv = 1.0f / (float)(deg > 1 ? deg : 1);
    const u32* base = (const u32*)in;
    int coloff = slice * 8 + sub;

    float a00 = 0.f, a01 = 0.f, a10 = 0.f, a11 = 0.f;
    float a20 = 0.f, a21 = 0.f, a30 = 0.f, a31 = 0.f;

    int o = o0;
    for (; o + 4 <= o1; o += 4) {
        int s0 = __builtin_nontemporal_load(&csr[o + 0]);
        int s1 = __builtin_nontemporal_load(&csr[o + 1]);
        int s2 = __builtin_nontemporal_load(&csr[o + 2]);
        int s3 = __builtin_nontemporal_load(&csr[o + 3]);
        u32 v0 = base[(size_t)s0 * ROWU32 + coloff];
        u32 v1 = base[(size_t)s1 * ROWU32 + coloff];
        u32 v2 = base[(size_t)s2 * ROWU32 + coloff];
        u32 v3 = base[(size_t)s3 * ROWU32 + coloff];
        a00 += b2f((u16)(v0 & 0xffffu)); a01 += b2f((u16)(v0 >> 16));
        a10 += b2f((u16)(v1 & 0xffffu)); a11 += b2f((u16)(v1 >> 16));
        a20 += b2f((u16)(v2 & 0xffffu)); a21 += b2f((u16)(v2 >> 16));
        a30 += b2f((u16)(v3 & 0xffffu)); a31 += b2f((u16)(v3 >> 16));
    }
    for (; o < o1; o++) {
        int s = __builtin_nontemporal_load(&csr[o]);
        u32 v = base[(size_t)s * ROWU32 + coloff];
        a00 += b2f((u16)(v & 0xffffu)); a01 += b2f((u16)(v >> 16));
    }
    float r0 = ((a00 + a10) + (a20 + a30)) * inv;
    float r1 = ((a01 + a11) + (a21 + a31)) * inv;
    u32 w = (u32)f2b(r0) | ((u32)f2b(r1) << 16);
    __builtin_nontemporal_store(w, &((u32*)out)[(size_t)n * ROWU32 + coloff]);
}

// ---------------- fused dual GEMM via MFMA ----------------

template<int KHALF>
__global__ __launch_bounds__(256)
void gemm_mfma(const u16* __restrict__ A1, const u16* __restrict__ A2,
               const u16* __restrict__ Wt, const float* __restrict__ bias,
               u16* __restrict__ out) {
    constexpr int KC  = 2 * KHALF;
    constexpr int NKS = KC / 32;

    int t = threadIdx.x;
    int lane = t & 63, w = t >> 6;
    int l15 = lane & 15, l4 = lane >> 4;
    int mbase = blockIdx.x * 64;

    bf16x8 bfr[2][NKS];
    #pragma unroll
    for (int ct = 0; ct < 2; ct++)
        #pragma unroll
        for (int ks = 0; ks < NKS; ks++) {
            int row = w * 32 + ct * 16 + l15;          // output col
            int kb  = ks * 32 + l4 * 8;
            bfr[ct][ks] = *reinterpret_cast<const bf16x8*>(Wt + row * KC + kb);
        }

    f32x4 acc[4][2];
    #pragma unroll
    for (int i = 0; i < 4; i++)
        #pragma unroll
        for (int j = 0; j < 2; j++)
            acc[i][j] = (f32x4){0.f, 0.f, 0.f, 0.f};

    const bf16x8 zfr = {0, 0, 0, 0, 0, 0, 0, 0};

    #pragma unroll
    for (int ks = 0; ks < NKS; ks++) {
        const u16* Ab = (ks < NKS / 2) ? A1 : A2;
        int kb = (ks < NKS / 2) ? (ks * 32 + l4 * 8) : ((ks - NKS / 2) * 32 + l4 * 8);
        bf16x8 afr[4];
        #pragma unroll
        for (int rt = 0; rt < 4; rt++) {
            int row = mbase + rt * 16 + l15;
            afr[rt] = (row < N_NODES)
                ? *reinterpret_cast<const bf16x8*>(Ab + (size_t)row * KHALF + kb)
                : zfr;
        }
        #pragma unroll
        for (int rt = 0; rt < 4; rt++)
            #pragma unroll
            for (int ct = 0; ct < 2; ct++)
                acc[rt][ct] = __builtin_amdgcn_mfma_f32_16x16x32_bf16(
                    afr[rt], bfr[ct][ks], acc[rt][ct], 0, 0, 0);
    }

    // epilogue: bias + relu, store bf16. C/D: col=lane&15, row=(lane>>4)*4+reg
    #pragma unroll
    for (int ct = 0; ct < 2; ct++) {
        int col = w * 32 + ct * 16 + l15;
        float bv = bias[col];
        #pragma unroll
        for (int rt = 0; rt < 4; rt++) {
            #pragma unroll
            for (int j = 0; j < 4; j++) {
                int row = mbase + rt * 16 + l4 * 4 + j;
                if (row < N_NODES) {
                    float v = fmaxf(acc[rt][ct][j] + bv, 0.f);
                    out[(size_t)row * 128 + col] = f2b(v);
                }
            }
        }
    }
}

// ---------------- pooling (parallel partial sums) + LN/decode ----------------

__global__ __launch_bounds__(128)
void pool_partial(const u16* __restrict__ h, const int* __restrict__ batch,
                  float* __restrict__ gpool) {
    int c = threadIdx.x;
    int n0 = blockIdx.x * POOL_CHUNK;
    int n1 = n0 + POOL_CHUNK; if (n1 > N_NODES) n1 = N_NODES;
    float run = 0.f;
    int curg = -1;
    for (int r = n0; r < n1; r++) {
        int gid = batch[r];
        if (gid != curg) {
            if (curg >= 0) atomicAdd(&gpool[curg * 128 + c], run);
            run = 0.f; curg = gid;
        }
        run += b2f(h[(size_t)r * 128 + c]);
    }
    if (curg >= 0) atomicAdd(&gpool[curg * 128 + c], run);
}

__global__ __launch_bounds__(64)
void ln_decode(const float* __restrict__ gpool,
               const float* __restrict__ ln_g, const float* __restrict__ ln_b,
               const float* __restrict__ Wd, const float* __restrict__ bd,
               float* __restrict__ out) {
    int g = blockIdx.x, lane = threadIdx.x;
    float v0 = gpool[g * 128 + lane];
    float v1 = gpool[g * 128 + 64 + lane];
    float s = v0 + v1;
    #pragma unroll
    for (int off = 32; off > 0; off >>= 1) s += __shfl_xor(s, off, 64);
    float mu = s * (1.0f / 128.f);
    float d0 = v0 - mu, d1 = v1 - mu;
    float q = d0 * d0 + d1 * d1;
    #pragma unroll
    for (int off = 32; off > 0; off >>= 1) q += __shfl_xor(q, off, 64);
    float rs = rsqrtf(q * (1.0f / 128.f) + LN_EPS);
    float gn0 = d0 * rs * ln_g[lane]      + ln_b[lane];
    float gn1 = d1 * rs * ln_g[64 + lane] + ln_b[64 + lane];
    float o0 = gn0 * Wd[lane * 2 + 0] + gn1 * Wd[(64 + lane) * 2 + 0];
    float o1 = gn0 * Wd[lane * 2 + 1] + gn1 * Wd[(64 + lane) * 2 + 1];
    #pragma unroll
    for (int off = 32; off > 0; off >>= 1) {
        o0 += __shfl_xor(o0, off, 64);
        o1 += __shfl_xor(o1, off, 64);
    }
    if (lane == 0) {
        out[g * 2 + 0] = o0 + bd[0];
        out[g * 2 + 1] = o1 + bd[1];
    }
}

// ---------------- host launcher ----------------

extern "C" void kernel_launch(void* const* d_in, const int* in_sizes, int n_in,
                              void* d_out, int out_size, void* d_ws, size_t ws_size,
                              hipStream_t stream) {
    (void)in_sizes; (void)n_in; (void)out_size; (void)ws_size;

    const float* x     = (const float*)d_in[0];
    const int*   ei    = (const int*)d_in[1];
    const int*   batch = (const int*)d_in[2];
    const float* Wl0 = (const float*)d_in[3];
    const float* bl0 = (const float*)d_in[4];
    const float* Wr0 = (const float*)d_in[5];
    const float* Wl1 = (const float*)d_in[6];
    const float* bl1 = (const float*)d_in[7];
    const float* Wr1 = (const float*)d_in[8];
    const float* Wl2 = (const float*)d_in[9];
    const float* bl2 = (const float*)d_in[10];
    const float* Wr2 = (const float*)d_in[11];
    const float* ln_g = (const float*)d_in[12];
    const float* ln_b = (const float*)d_in[13];
    const float* Wd  = (const float*)d_in[14];
    const float* bd  = (const float*)d_in[15];
    float* out = (float*)d_out;

    const int* src = ei;
    const int* dst = ei + N_EDGES;

    // workspace layout (bytes)
    char* ws = (char*)d_ws;
    int*   csr     = (int*)(ws + 0);             //  6,400,000
    int*   offsets = (int*)(ws + 6400000);       //    400,128
    int*   bcnt    = (int*)(ws + 6800128);       //      1,024
    int*   bbase   = (int*)(ws + 6801152);       //      1,024
    uint2* bpool   = (uint2*)(ws + 6802176);     // 16,777,216
    u16*   x16     = (u16*)(ws + 23579392);      // 12,800,000
    u16*   aggbuf  = (u16*)(ws + 36379392);      // 25,600,000
    u16*   bufB    = (u16*)(ws + 61979392);      // 25,600,000
    u16*   bufC    = (u16*)(ws + 87579392);      // 25,600,000
    u16*   Wt0     = (u16*)(ws + 113179392);     //     32,768
    u16*   Wt1     = (u16*)(ws + 113212160);     //     65,536
    u16*   Wt2     = (u16*)(ws + 113277696);     //     65,536
    float* gpool   = (float*)(ws + 113343232);   //    262,144
    // total: 113,605,376 bytes

    hipMemsetAsync(bcnt, 0, NB * sizeof(int), stream);
    hipMemsetAsync(gpool, 0, N_GRAPHS * 128 * sizeof(float), stream);

    partition_edges<<<PBLOCKS, 256, 0, stream>>>(src, dst, bcnt, bpool);
    scan_buckets<<<1, 256, 0, stream>>>(bcnt, bbase, offsets);
    build_csr_bucket<<<NB, 256, 0, stream>>>(bcnt, bbase, bpool, offsets, csr);

    // conversions
    conv_f32_bf16<<<(N_NODES * 64 / 4 + 255) / 256, 256, 0, stream>>>(x, x16, N_NODES * 64 / 4);
    conv_weights<<<(128 * 128 + 255) / 256, 256, 0, stream>>>(Wl0, Wr0, 64, 128, Wt0);
    conv_weights<<<(128 * 256 + 255) / 256, 256, 0, stream>>>(Wl1, Wr1, 128, 256, Wt1);
    conv_weights<<<(128 * 256 + 255) / 256, 256, 0, stream>>>(Wl2, Wr2, 128, 256, Wt2);

    const int agg128Grid = 8 * (N_NODES / 32);      // 25000 (slices x chunks)
    const int agg64Grid  = 4 * (N_NODES / 32);      // 12500
    const int gemmGrid   = (N_NODES + 63) / 64;     // 1563

    // layer 0  (64ch input: 4 slices of 16ch)
    aggregate_slice<32, 4><<<agg64Grid, 256, 0, stream>>>(x16, offsets, csr, aggbuf);
    gemm_mfma<64><<<gemmGrid, 256, 0, stream>>>(aggbuf, x16, Wt0, bl0, bufB);
    // layer 1  (128ch: 8 slices of 16ch)
    aggregate_slice<64, 8><<<agg128Grid, 256, 0, stream>>>(bufB, offsets, csr, aggbuf);
    gemm_mfma<128><<<gemmGrid, 256, 0, stream>>>(aggbuf, bufB, Wt1, bl1, bufC);
    // layer 2
    aggregate_slice<64, 8><<<agg128Grid, 256, 0, stream>>>(bufC, offsets, csr, aggbuf);
    gemm_mfma<128><<<gemmGrid, 256, 0, stream>>>(aggbuf, bufC, Wt2, bl2, bufB);

    // pool + LN + decode
    pool_partial<<<POOL_BLOCKS, 128, 0, stream>>>(bufB, batch, gpool);
    ln_decode<<<N_GRAPHS, 64, 0, stream>>>(gpool, ln_g, ln_b, Wd, bd, out);
}

// Round 8
// 426.125 us; speedup vs baseline: 1.7986x; 1.7986x over previous
//
#include <hip/hip_runtime.h>

#define N_NODES  100000
#define N_EDGES  1600000
#define N_GRAPHS 512
#define LN_EPS   1e-5f

#define NB    256          // dst buckets
#define NPB   391          // nodes per bucket (256*391 = 100096 >= N_NODES)
#define BCAP  8192         // pool capacity per bucket
#define PCHUNK 8192
#define PBLOCKS ((N_EDGES + PCHUNK - 1) / PCHUNK)   // 196
#define POOL_CHUNK 64
#define POOL_BLOCKS ((N_NODES + POOL_CHUNK - 1) / POOL_CHUNK)  // 1563

typedef unsigned short u16;
typedef unsigned int   u32;
typedef __attribute__((ext_vector_type(8))) short bf16x8;
typedef __attribute__((ext_vector_type(4))) float f32x4;

__device__ __forceinline__ float b2f(u16 v) {
    u32 u = ((u32)v) << 16;
    return __builtin_bit_cast(float, u);
}
__device__ __forceinline__ u16 f2b(float f) {
    u32 u = __builtin_bit_cast(u32, f);
    u32 r = (u + 0x7fffu + ((u >> 16) & 1u)) >> 16;  // RNE
    return (u16)r;
}

// ---------------- bucketed CSR build ----------------

__global__ __launch_bounds__(256)
void partition_edges(const int* __restrict__ src, const int* __restrict__ dst,
                     int* __restrict__ bcnt, uint2* __restrict__ bpool) {
    __shared__ int hist[NB];
    __shared__ int gbase[NB];
    __shared__ int cur[NB];
    int t = threadIdx.x;
    int e0 = blockIdx.x * PCHUNK;
    int e1 = e0 + PCHUNK; if (e1 > N_EDGES) e1 = N_EDGES;

    hist[t] = 0;
    __syncthreads();
    for (int e = e0 + t; e < e1; e += 256)
        atomicAdd(&hist[dst[e] / NPB], 1);
    __syncthreads();
    int h = hist[t];
    gbase[t] = (h > 0) ? atomicAdd(&bcnt[t], h) : 0;
    cur[t] = 0;
    __syncthreads();
    for (int e = e0 + t; e < e1; e += 256) {
        int d = dst[e], s = src[e];
        int b = d / NPB;
        int p = atomicAdd(&cur[b], 1);
        bpool[(size_t)b * BCAP + gbase[b] + p] = make_uint2((u32)d, (u32)s);
    }
}

__global__ void scan_buckets(const int* __restrict__ bcnt, int* __restrict__ bbase,
                             int* __restrict__ offsets) {
    __shared__ int sh[NB];
    int t = threadIdx.x;
    int v = bcnt[t];
    sh[t] = v; __syncthreads();
    for (int off = 1; off < NB; off <<= 1) {
        int add = (t >= off) ? sh[t - off] : 0;
        __syncthreads();
        sh[t] += add;
        __syncthreads();
    }
    bbase[t] = sh[t] - v;                         // exclusive
    if (t == NB - 1) offsets[N_NODES] = sh[t];    // == N_EDGES
}

__global__ __launch_bounds__(256)
void build_csr_bucket(const int* __restrict__ bcnt, const int* __restrict__ bbase,
                      const uint2* __restrict__ bpool,
                      int* __restrict__ offsets, int* __restrict__ csr) {
    __shared__ int sA[512];
    __shared__ int sB[512];
    __shared__ int csrL[BCAP];
    int b = blockIdx.x, t = threadIdx.x;
    int nlo = b * NPB;
    int NL = N_NODES - nlo; if (NL > NPB) NL = NPB;
    int count = bcnt[b], base = bbase[b];
    const uint2* pool = bpool + (size_t)b * BCAP;

    sA[t] = 0; sA[t + 256] = 0;
    __syncthreads();
    for (int i = t; i < count; i += 256)
        atomicAdd(&sA[(int)pool[i].x - nlo], 1);
    __syncthreads();
    int c0 = sA[t], c1 = sA[t + 256];

    int* a = sA; int* c = sB;
    for (int off = 1; off < 512; off <<= 1) {
        c[t]       = a[t]       + ((t >= off)       ? a[t - off]       : 0);
        c[t + 256] = a[t + 256] + ((t + 256 >= off) ? a[t + 256 - off] : 0);
        __syncthreads();
        int* tmp = a; a = c; c = tmp;
    }
    int ex0 = a[t] - c0, ex1 = a[t + 256] - c1;   // exclusive
    if (t < NL)       offsets[nlo + t]       = base + ex0;
    if (t + 256 < NL) offsets[nlo + t + 256] = base + ex1;
    c[t] = ex0; c[t + 256] = ex1;
    __syncthreads();
    for (int i = t; i < count; i += 256) {
        uint2 p = pool[i];
        int pos = atomicAdd(&c[(int)p.x - nlo], 1);
        csrL[pos] = (int)p.y;
    }
    __syncthreads();
    for (int i = t; i < count; i += 256)
        csr[base + i] = csrL[i];
}

// ---------------- dtype conversions ----------------

__global__ __launch_bounds__(256)
void conv_f32_bf16(const float* __restrict__ in, u16* __restrict__ out, int n4) {
    int i = blockIdx.x * 256 + threadIdx.x;
    if (i < n4) {
        float4 v = ((const float4*)in)[i];
        u32 lo = (u32)f2b(v.x) | ((u32)f2b(v.y) << 16);
        u32 hi = (u32)f2b(v.z) | ((u32)f2b(v.w) << 16);
        ((uint2*)out)[i] = make_uint2(lo, hi);
    }
}

__global__ __launch_bounds__(256)
void conv_weights(const float* __restrict__ Wl, const float* __restrict__ Wr,
                  int K1, int KC, u16* __restrict__ Wt) {
    int idx = blockIdx.x * 256 + threadIdx.x;
    if (idx >= 128 * KC) return;
    int c = idx / KC, k = idx % KC;
    float v = (k < K1) ? Wl[k * 128 + c] : Wr[(k - K1) * 128 + c];
    Wt[idx] = f2b(v);
}

// ---------------- fused SAGE layer: aggregate -> LDS -> dual GEMM ----------------
// out[n] = relu( mean_{s in N(n)} feat[s] @ Wl  +  feat[n] @ Wr + bias )
// Wt[128][2*KHALF] = [Wl^T | Wr^T] (per output channel, concatenated K).
// Block: 256 thr = 4 waves, 64 output rows.
// Phase 1: gather-aggregate the block's 64 rows into LDS (bf16, padded rows).
// Phase 2: MFMA; A1 fragments from LDS (row stride 272B/144B: 17|9 x16B ->
// bank-floor access), A2 from global, B register-resident. Across blocks,
// phase-1 memory and phase-2 MFMA overlap.

template<int KHALF>
__global__ __launch_bounds__(256)
void sage_layer(const u16* __restrict__ feat, const int* __restrict__ offsets,
                const int* __restrict__ csr, const u16* __restrict__ Wt,
                const float* __restrict__ bias, u16* __restrict__ out) {
    constexpr int KC     = 2 * KHALF;
    constexpr int NKS    = KC / 32;
    constexpr int ROWU32 = KHALF / 2;        // u32 per feature row
    constexpr int LROW   = ROWU32 + 4;       // padded LDS row stride (u32)

    __shared__ __align__(16) u32 lds_a[64 * LROW];

    int t = threadIdx.x;
    int lane = t & 63, w = t >> 6;
    int l15 = lane & 15, l4 = lane >> 4;
    int mbase = blockIdx.x * 64;

    // ---- Phase 1: aggregate 64 nodes into LDS ----
    {
        int grp = t >> 5;          // 0..7 node-group
        int sub = t & 31;
        #pragma unroll 1
        for (int nn = 0; nn < 8; nn++) {
            int nl = grp * 8 + nn;
            int n = mbase + nl;
            if (n < N_NODES) {
                int o0 = offsets[n], o1 = offsets[n + 1];
                int deg = o1 - o0;
                float inv = 1.0f / (float)(deg > 1 ? deg : 1);
                if constexpr (KHALF == 128) {
                    const uint2* base = (const uint2*)feat;   // row stride 32 uint2
                    float a00=0.f,a01=0.f,a02=0.f,a03=0.f;
                    float a10=0.f,a11=0.f,a12=0.f,a13=0.f;
                    float a20=0.f,a21=0.f,a22=0.f,a23=0.f;
                    float a30=0.f,a31=0.f,a32=0.f,a33=0.f;
                    int o = o0;
                    for (; o + 4 <= o1; o += 4) {
                        int s0 = csr[o+0], s1 = csr[o+1], s2 = csr[o+2], s3 = csr[o+3];
                        uint2 v0 = base[(size_t)s0 * 32 + sub];
                        uint2 v1 = base[(size_t)s1 * 32 + sub];
                        uint2 v2 = base[(size_t)s2 * 32 + sub];
                        uint2 v3 = base[(size_t)s3 * 32 + sub];
                        a00 += b2f((u16)(v0.x & 0xffffu)); a01 += b2f((u16)(v0.x >> 16));
                        a02 += b2f((u16)(v0.y & 0xffffu)); a03 += b2f((u16)(v0.y >> 16));
                        a10 += b2f((u16)(v1.x & 0xffffu)); a11 += b2f((u16)(v1.x >> 16));
                        a12 += b2f((u16)(v1.y & 0xffffu)); a13 += b2f((u16)(v1.y >> 16));
                        a20 += b2f((u16)(v2.x & 0xffffu)); a21 += b2f((u16)(v2.x >> 16));
                        a22 += b2f((u16)(v2.y & 0xffffu)); a23 += b2f((u16)(v2.y >> 16));
                        a30 += b2f((u16)(v3.x & 0xffffu)); a31 += b2f((u16)(v3.x >> 16));
                        a32 += b2f((u16)(v3.y & 0xffffu)); a33 += b2f((u16)(v3.y >> 16));
                    }
                    for (; o < o1; o++) {
                        int s = csr[o];
                        uint2 v = base[(size_t)s * 32 + sub];
                        a00 += b2f((u16)(v.x & 0xffffu)); a01 += b2f((u16)(v.x >> 16));
                        a02 += b2f((u16)(v.y & 0xffffu)); a03 += b2f((u16)(v.y >> 16));
                    }
                    float r0 = ((a00+a10)+(a20+a30)) * inv;
                    float r1 = ((a01+a11)+(a21+a31)) * inv;
                    float r2 = ((a02+a12)+(a22+a32)) * inv;
                    float r3 = ((a03+a13)+(a23+a33)) * inv;
                    lds_a[nl*LROW + sub*2 + 0] = (u32)f2b(r0) | ((u32)f2b(r1) << 16);
                    lds_a[nl*LROW + sub*2 + 1] = (u32)f2b(r2) | ((u32)f2b(r3) << 16);
                } else {
                    const u32* base = (const u32*)feat;       // row stride 32 u32
                    float a00=0.f,a01=0.f,a10=0.f,a11=0.f;
                    float a20=0.f,a21=0.f,a30=0.f,a31=0.f;
                    int o = o0;
                    for (; o + 4 <= o1; o += 4) {
                        int s0 = csr[o+0], s1 = csr[o+1], s2 = csr[o+2], s3 = csr[o+3];
                        u32 v0 = base[(size_t)s0 * 32 + sub];
                        u32 v1 = base[(size_t)s1 * 32 + sub];
                        u32 v2 = base[(size_t)s2 * 32 + sub];
                        u32 v3 = base[(size_t)s3 * 32 + sub];
                        a00 += b2f((u16)(v0 & 0xffffu)); a01 += b2f((u16)(v0 >> 16));
                        a10 += b2f((u16)(v1 & 0xffffu)); a11 += b2f((u16)(v1 >> 16));
                        a20 += b2f((u16)(v2 & 0xffffu)); a21 += b2f((u16)(v2 >> 16));
                        a30 += b2f((u16)(v3 & 0xffffu)); a31 += b2f((u16)(v3 >> 16));
                    }
                    for (; o < o1; o++) {
                        int s = csr[o];
                        u32 v = base[(size_t)s * 32 + sub];
                        a00 += b2f((u16)(v & 0xffffu)); a01 += b2f((u16)(v >> 16));
                    }
                    float r0 = ((a00+a10)+(a20+a30)) * inv;
                    float r1 = ((a01+a11)+(a21+a31)) * inv;
                    lds_a[nl*LROW + sub] = (u32)f2b(r0) | ((u32)f2b(r1) << 16);
                }
            } else {
                if constexpr (KHALF == 128) {
                    lds_a[nl*LROW + sub*2 + 0] = 0;
                    lds_a[nl*LROW + sub*2 + 1] = 0;
                } else {
                    lds_a[nl*LROW + sub] = 0;
                }
            }
        }
    }
    __syncthreads();

    // ---- Phase 2: dual GEMM ----
    bf16x8 bfr[2][NKS];
    #pragma unroll
    for (int ct = 0; ct < 2; ct++)
        #pragma unroll
        for (int ks = 0; ks < NKS; ks++) {
            int row = w * 32 + ct * 16 + l15;          // output col
            int kb  = ks * 32 + l4 * 8;
            bfr[ct][ks] = *reinterpret_cast<const bf16x8*>(Wt + row * KC + kb);
        }

    f32x4 acc[4][2];
    #pragma unroll
    for (int i = 0; i < 4; i++)
        #pragma unroll
        for (int j = 0; j < 2; j++)
            acc[i][j] = (f32x4){0.f, 0.f, 0.f, 0.f};

    const bf16x8 zfr = {0, 0, 0, 0, 0, 0, 0, 0};

    #pragma unroll
    for (int ks = 0; ks < NKS; ks++) {
        bf16x8 afr[4];
        if (ks < NKS / 2) {
            // A1 (aggregated) from LDS
            #pragma unroll
            for (int rt = 0; rt < 4; rt++) {
                int rl = rt * 16 + l15;
                afr[rt] = *reinterpret_cast<const bf16x8*>(
                    &lds_a[rl * LROW + ks * 16 + l4 * 4]);
            }
        } else {
            // A2 (self features) from global
            int kb = (ks - NKS / 2) * 32 + l4 * 8;
            #pragma unroll
            for (int rt = 0; rt < 4; rt++) {
                int row = mbase + rt * 16 + l15;
                afr[rt] = (row < N_NODES)
                    ? *reinterpret_cast<const bf16x8*>(feat + (size_t)row * KHALF + kb)
                    : zfr;
            }
        }
        #pragma unroll
        for (int rt = 0; rt < 4; rt++)
            #pragma unroll
            for (int ct = 0; ct < 2; ct++)
                acc[rt][ct] = __builtin_amdgcn_mfma_f32_16x16x32_bf16(
                    afr[rt], bfr[ct][ks], acc[rt][ct], 0, 0, 0);
    }

    // epilogue: bias + relu, store bf16. C/D: col=lane&15, row=(lane>>4)*4+reg
    #pragma unroll
    for (int ct = 0; ct < 2; ct++) {
        int col = w * 32 + ct * 16 + l15;
        float bv = bias[col];
        #pragma unroll
        for (int rt = 0; rt < 4; rt++) {
            #pragma unroll
            for (int j = 0; j < 4; j++) {
                int row = mbase + rt * 16 + l4 * 4 + j;
                if (row < N_NODES) {
                    float v = fmaxf(acc[rt][ct][j] + bv, 0.f);
                    out[(size_t)row * 128 + col] = f2b(v);
                }
            }
        }
    }
}

// ---------------- pooling (parallel partial sums) + LN/decode ----------------

__global__ __launch_bounds__(128)
void pool_partial(const u16* __restrict__ h, const int* __restrict__ batch,
                  float* __restrict__ gpool) {
    int c = threadIdx.x;
    int n0 = blockIdx.x * POOL_CHUNK;
    int n1 = n0 + POOL_CHUNK; if (n1 > N_NODES) n1 = N_NODES;
    float run = 0.f;
    int curg = -1;
    for (int r = n0; r < n1; r++) {
        int gid = batch[r];
        if (gid != curg) {
            if (curg >= 0) atomicAdd(&gpool[curg * 128 + c], run);
            run = 0.f; curg = gid;
        }
        run += b2f(h[(size_t)r * 128 + c]);
    }
    if (curg >= 0) atomicAdd(&gpool[curg * 128 + c], run);
}

__global__ __launch_bounds__(64)
void ln_decode(const float* __restrict__ gpool,
               const float* __restrict__ ln_g, const float* __restrict__ ln_b,
               const float* __restrict__ Wd, const float* __restrict__ bd,
               float* __restrict__ out) {
    int g = blockIdx.x, lane = threadIdx.x;
    float v0 = gpool[g * 128 + lane];
    float v1 = gpool[g * 128 + 64 + lane];
    float s = v0 + v1;
    #pragma unroll
    for (int off = 32; off > 0; off >>= 1) s += __shfl_xor(s, off, 64);
    float mu = s * (1.0f / 128.f);
    float d0 = v0 - mu, d1 = v1 - mu;
    float q = d0 * d0 + d1 * d1;
    #pragma unroll
    for (int off = 32; off > 0; off >>= 1) q += __shfl_xor(q, off, 64);
    float rs = rsqrtf(q * (1.0f / 128.f) + LN_EPS);
    float gn0 = d0 * rs * ln_g[lane]      + ln_b[lane];
    float gn1 = d1 * rs * ln_g[64 + lane] + ln_b[64 + lane];
    float o0 = gn0 * Wd[lane * 2 + 0] + gn1 * Wd[(64 + lane) * 2 + 0];
    float o1 = gn0 * Wd[lane * 2 + 1] + gn1 * Wd[(64 + lane) * 2 + 1];
    #pragma unroll
    for (int off = 32; off > 0; off >>= 1) {
        o0 += __shfl_xor(o0, off, 64);
        o1 += __shfl_xor(o1, off, 64);
    }
    if (lane == 0) {
        out[g * 2 + 0] = o0 + bd[0];
        out[g * 2 + 1] = o1 + bd[1];
    }
}

// ---------------- host launcher ----------------

extern "C" void kernel_launch(void* const* d_in, const int* in_sizes, int n_in,
                              void* d_out, int out_size, void* d_ws, size_t ws_size,
                              hipStream_t stream) {
    (void)in_sizes; (void)n_in; (void)out_size; (void)ws_size;

    const float* x     = (const float*)d_in[0];
    const int*   ei    = (const int*)d_in[1];
    const int*   batch = (const int*)d_in[2];
    const float* Wl0 = (const float*)d_in[3];
    const float* bl0 = (const float*)d_in[4];
    const float* Wr0 = (const float*)d_in[5];
    const float* Wl1 = (const float*)d_in[6];
    const float* bl1 = (const float*)d_in[7];
    const float* Wr1 = (const float*)d_in[8];
    const float* Wl2 = (const float*)d_in[9];
    const float* bl2 = (const float*)d_in[10];
    const float* Wr2 = (const float*)d_in[11];
    const float* ln_g = (const float*)d_in[12];
    const float* ln_b = (const float*)d_in[13];
    const float* Wd  = (const float*)d_in[14];
    const float* bd  = (const float*)d_in[15];
    float* out = (float*)d_out;

    const int* src = ei;
    const int* dst = ei + N_EDGES;

    // workspace layout (bytes)
    char* ws = (char*)d_ws;
    int*   csr     = (int*)(ws + 0);             //  6,400,000
    int*   offsets = (int*)(ws + 6400000);       //    400,128
    int*   bcnt    = (int*)(ws + 6800128);       //      1,024
    int*   bbase   = (int*)(ws + 6801152);       //      1,024
    uint2* bpool   = (uint2*)(ws + 6802176);     // 16,777,216
    u16*   x16     = (u16*)(ws + 23579392);      // 12,800,000
    u16*   bufB    = (u16*)(ws + 61979392);      // 25,600,000
    u16*   bufC    = (u16*)(ws + 87579392);      // 25,600,000
    u16*   Wt0     = (u16*)(ws + 113179392);     //     32,768
    u16*   Wt1     = (u16*)(ws + 113212160);     //     65,536
    u16*   Wt2     = (u16*)(ws + 113277696);     //     65,536
    float* gpool   = (float*)(ws + 113343232);   //    262,144
    // total: 113,605,376 bytes

    hipMemsetAsync(bcnt, 0, NB * sizeof(int), stream);
    hipMemsetAsync(gpool, 0, N_GRAPHS * 128 * sizeof(float), stream);

    partition_edges<<<PBLOCKS, 256, 0, stream>>>(src, dst, bcnt, bpool);
    scan_buckets<<<1, 256, 0, stream>>>(bcnt, bbase, offsets);
    build_csr_bucket<<<NB, 256, 0, stream>>>(bcnt, bbase, bpool, offsets, csr);

    // conversions
    conv_f32_bf16<<<(N_NODES * 64 / 4 + 255) / 256, 256, 0, stream>>>(x, x16, N_NODES * 64 / 4);
    conv_weights<<<(128 * 128 + 255) / 256, 256, 0, stream>>>(Wl0, Wr0, 64, 128, Wt0);
    conv_weights<<<(128 * 256 + 255) / 256, 256, 0, stream>>>(Wl1, Wr1, 128, 256, Wt1);
    conv_weights<<<(128 * 256 + 255) / 256, 256, 0, stream>>>(Wl2, Wr2, 128, 256, Wt2);

    const int layerGrid = (N_NODES + 63) / 64;     // 1563

    // fused layers: aggregate -> LDS -> dual GEMM
    sage_layer<64><<<layerGrid, 256, 0, stream>>>(x16, offsets, csr, Wt0, bl0, bufB);
    sage_layer<128><<<layerGrid, 256, 0, stream>>>(bufB, offsets, csr, Wt1, bl1, bufC);
    sage_layer<128><<<layerGrid, 256, 0, stream>>>(bufC, offsets, csr, Wt2, bl2, bufB);

    // pool + LN + decode
    pool_partial<<<POOL_BLOCKS, 128, 0, stream>>>(bufB, batch, gpool);
    ln_decode<<<N_GRAPHS, 64, 0, stream>>>(gpool, ln_g, ln_b, Wd, bd, out);
}

// Round 9
// 340.949 us; speedup vs baseline: 2.2479x; 1.2498x over previous
//
#include <hip/hip_runtime.h>

#define N_NODES  100000
#define N_EDGES  1600000
#define N_GRAPHS 512
#define LN_EPS   1e-5f

#define NB    256          // dst buckets
#define NPB   391          // nodes per bucket (256*391 = 100096 >= N_NODES)
#define BCAP  8192         // pool capacity per bucket
#define PCHUNK 8192
#define PBLOCKS ((N_EDGES + PCHUNK - 1) / PCHUNK)   // 196
#define POOL_CHUNK 64
#define POOL_BLOCKS ((N_NODES + POOL_CHUNK - 1) / POOL_CHUNK)  // 1563

typedef unsigned short u16;
typedef unsigned int   u32;
typedef __attribute__((ext_vector_type(8))) short bf16x8;
typedef __attribute__((ext_vector_type(4))) float f32x4;

__device__ __forceinline__ float b2f(u16 v) {
    u32 u = ((u32)v) << 16;
    return __builtin_bit_cast(float, u);
}
__device__ __forceinline__ u16 f2b(float f) {
    u32 u = __builtin_bit_cast(u32, f);
    u32 r = (u + 0x7fffu + ((u >> 16) & 1u)) >> 16;  // RNE
    return (u16)r;
}

// ---------------- bucketed CSR build ----------------

__global__ __launch_bounds__(256)
void partition_edges(const int* __restrict__ src, const int* __restrict__ dst,
                     int* __restrict__ bcnt, uint2* __restrict__ bpool) {
    __shared__ int hist[NB];
    __shared__ int gbase[NB];
    __shared__ int cur[NB];
    int t = threadIdx.x;
    int e0 = blockIdx.x * PCHUNK;
    int e1 = e0 + PCHUNK; if (e1 > N_EDGES) e1 = N_EDGES;

    hist[t] = 0;
    __syncthreads();
    for (int e = e0 + t; e < e1; e += 256)
        atomicAdd(&hist[dst[e] / NPB], 1);
    __syncthreads();
    int h = hist[t];
    gbase[t] = (h > 0) ? atomicAdd(&bcnt[t], h) : 0;
    cur[t] = 0;
    __syncthreads();
    for (int e = e0 + t; e < e1; e += 256) {
        int d = dst[e], s = src[e];
        int b = d / NPB;
        int p = atomicAdd(&cur[b], 1);
        bpool[(size_t)b * BCAP + gbase[b] + p] = make_uint2((u32)d, (u32)s);
    }
}

__global__ void scan_buckets(const int* __restrict__ bcnt, int* __restrict__ bbase,
                             int* __restrict__ offsets) {
    __shared__ int sh[NB];
    int t = threadIdx.x;
    int v = bcnt[t];
    sh[t] = v; __syncthreads();
    for (int off = 1; off < NB; off <<= 1) {
        int add = (t >= off) ? sh[t - off] : 0;
        __syncthreads();
        sh[t] += add;
        __syncthreads();
    }
    bbase[t] = sh[t] - v;                         // exclusive
    if (t == NB - 1) offsets[N_NODES] = sh[t];    // == N_EDGES
}

__global__ __launch_bounds__(256)
void build_csr_bucket(const int* __restrict__ bcnt, const int* __restrict__ bbase,
                      const uint2* __restrict__ bpool,
                      int* __restrict__ offsets, int* __restrict__ csr) {
    __shared__ int sA[512];
    __shared__ int sB[512];
    __shared__ int csrL[BCAP];
    int b = blockIdx.x, t = threadIdx.x;
    int nlo = b * NPB;
    int NL = N_NODES - nlo; if (NL > NPB) NL = NPB;
    int count = bcnt[b], base = bbase[b];
    const uint2* pool = bpool + (size_t)b * BCAP;

    sA[t] = 0; sA[t + 256] = 0;
    __syncthreads();
    for (int i = t; i < count; i += 256)
        atomicAdd(&sA[(int)pool[i].x - nlo], 1);
    __syncthreads();
    int c0 = sA[t], c1 = sA[t + 256];

    int* a = sA; int* c = sB;
    for (int off = 1; off < 512; off <<= 1) {
        c[t]       = a[t]       + ((t >= off)       ? a[t - off]       : 0);
        c[t + 256] = a[t + 256] + ((t + 256 >= off) ? a[t + 256 - off] : 0);
        __syncthreads();
        int* tmp = a; a = c; c = tmp;
    }
    int ex0 = a[t] - c0, ex1 = a[t + 256] - c1;   // exclusive
    if (t < NL)       offsets[nlo + t]       = base + ex0;
    if (t + 256 < NL) offsets[nlo + t + 256] = base + ex1;
    c[t] = ex0; c[t + 256] = ex1;
    __syncthreads();
    for (int i = t; i < count; i += 256) {
        uint2 p = pool[i];
        int pos = atomicAdd(&c[(int)p.x - nlo], 1);
        csrL[pos] = (int)p.y;
    }
    __syncthreads();
    for (int i = t; i < count; i += 256)
        csr[base + i] = csrL[i];
}

// ---------------- dtype conversions ----------------

__global__ __launch_bounds__(256)
void conv_f32_bf16(const float* __restrict__ in, u16* __restrict__ out, int n4) {
    int i = blockIdx.x * 256 + threadIdx.x;
    if (i < n4) {
        float4 v = ((const float4*)in)[i];
        u32 lo = (u32)f2b(v.x) | ((u32)f2b(v.y) << 16);
        u32 hi = (u32)f2b(v.z) | ((u32)f2b(v.w) << 16);
        ((uint2*)out)[i] = make_uint2(lo, hi);
    }
}

__global__ __launch_bounds__(256)
void conv_weights(const float* __restrict__ Wl, const float* __restrict__ Wr,
                  int K1, int KC, u16* __restrict__ Wt) {
    int idx = blockIdx.x * 256 + threadIdx.x;
    if (idx >= 128 * KC) return;
    int c = idx / KC, k = idx % KC;
    float v = (k < K1) ? Wl[k * 128 + c] : Wr[(k - K1) * 128 + c];
    Wt[idx] = f2b(v);
}

// ---------------- mean aggregation (bf16 gather via CSR) ----------------
// 32 lanes per node, 8 nodes per 256-thr block, 4-way edge unroll.  (r6-verified)

template<int F>
__global__ __launch_bounds__(256)
void aggregate_bf16(const u16* __restrict__ in, const int* __restrict__ offsets,
                    const int* __restrict__ csr, u16* __restrict__ out) {
    int grp = threadIdx.x >> 5;
    int sub = threadIdx.x & 31;
    int n = blockIdx.x * 8 + grp;     // grid 12500 * 8 == N_NODES exactly
    int o0 = offsets[n], o1 = offsets[n + 1];
    int d = o1 - o0;
    float inv = 1.0f / (float)(d > 1 ? d : 1);

    if (F == 128) {
        const uint2* base = (const uint2*)in;      // row stride 32 uint2
        float acc[4][4];
        #pragma unroll
        for (int j = 0; j < 4; j++)
            #pragma unroll
            for (int c = 0; c < 4; c++) acc[j][c] = 0.f;

        int o = o0;
        for (; o + 4 <= o1; o += 4) {
            int s0 = csr[o + 0], s1 = csr[o + 1], s2 = csr[o + 2], s3 = csr[o + 3];
            uint2 v0 = base[(size_t)s0 * 32 + sub];
            uint2 v1 = base[(size_t)s1 * 32 + sub];
            uint2 v2 = base[(size_t)s2 * 32 + sub];
            uint2 v3 = base[(size_t)s3 * 32 + sub];
            acc[0][0] += b2f((u16)(v0.x & 0xffffu)); acc[0][1] += b2f((u16)(v0.x >> 16));
            acc[0][2] += b2f((u16)(v0.y & 0xffffu)); acc[0][3] += b2f((u16)(v0.y >> 16));
            acc[1][0] += b2f((u16)(v1.x & 0xffffu)); acc[1][1] += b2f((u16)(v1.x >> 16));
            acc[1][2] += b2f((u16)(v1.y & 0xffffu)); acc[1][3] += b2f((u16)(v1.y >> 16));
            acc[2][0] += b2f((u16)(v2.x & 0xffffu)); acc[2][1] += b2f((u16)(v2.x >> 16));
            acc[2][2] += b2f((u16)(v2.y & 0xffffu)); acc[2][3] += b2f((u16)(v2.y >> 16));
            acc[3][0] += b2f((u16)(v3.x & 0xffffu)); acc[3][1] += b2f((u16)(v3.x >> 16));
            acc[3][2] += b2f((u16)(v3.y & 0xffffu)); acc[3][3] += b2f((u16)(v3.y >> 16));
        }
        for (; o < o1; o++) {
            int s = csr[o];
            uint2 v = base[(size_t)s * 32 + sub];
            acc[0][0] += b2f((u16)(v.x & 0xffffu)); acc[0][1] += b2f((u16)(v.x >> 16));
            acc[0][2] += b2f((u16)(v.y & 0xffffu)); acc[0][3] += b2f((u16)(v.y >> 16));
        }
        float r0 = ((acc[0][0] + acc[1][0]) + (acc[2][0] + acc[3][0])) * inv;
        float r1 = ((acc[0][1] + acc[1][1]) + (acc[2][1] + acc[3][1])) * inv;
        float r2 = ((acc[0][2] + acc[1][2]) + (acc[2][2] + acc[3][2])) * inv;
        float r3 = ((acc[0][3] + acc[1][3]) + (acc[2][3] + acc[3][3])) * inv;
        uint2 w;
        w.x = (u32)f2b(r0) | ((u32)f2b(r1) << 16);
        w.y = (u32)f2b(r2) | ((u32)f2b(r3) << 16);
        ((uint2*)out)[(size_t)n * 32 + sub] = w;
    } else {
        const u32* base = (const u32*)in;          // row stride 32 u32
        float acc[4][2];
        #pragma unroll
        for (int j = 0; j < 4; j++) { acc[j][0] = 0.f; acc[j][1] = 0.f; }

        int o = o0;
        for (; o + 4 <= o1; o += 4) {
            int s0 = csr[o + 0], s1 = csr[o + 1], s2 = csr[o + 2], s3 = csr[o + 3];
            u32 v0 = base[(size_t)s0 * 32 + sub];
            u32 v1 = base[(size_t)s1 * 32 + sub];
            u32 v2 = base[(size_t)s2 * 32 + sub];
            u32 v3 = base[(size_t)s3 * 32 + sub];
            acc[0][0] += b2f((u16)(v0 & 0xffffu)); acc[0][1] += b2f((u16)(v0 >> 16));
            acc[1][0] += b2f((u16)(v1 & 0xffffu)); acc[1][1] += b2f((u16)(v1 >> 16));
            acc[2][0] += b2f((u16)(v2 & 0xffffu)); acc[2][1] += b2f((u16)(v2 >> 16));
            acc[3][0] += b2f((u16)(v3 & 0xffffu)); acc[3][1] += b2f((u16)(v3 >> 16));
        }
        for (; o < o1; o++) {
            int s = csr[o];
            u32 v = base[(size_t)s * 32 + sub];
            acc[0][0] += b2f((u16)(v & 0xffffu)); acc[0][1] += b2f((u16)(v >> 16));
        }
        float r0 = ((acc[0][0] + acc[1][0]) + (acc[2][0] + acc[3][0])) * inv;
        float r1 = ((acc[0][1] + acc[1][1]) + (acc[2][1] + acc[3][1])) * inv;
        ((u32*)out)[(size_t)n * 32 + sub] = (u32)f2b(r0) | ((u32)f2b(r1) << 16);
    }
}

// ---------------- fused dual GEMM via MFMA, LDS-staged A ----------------
// out[M][128] = relu( A1[M][KHALF]@W1 + A2[M][KHALF]@W2 + bias ), bf16, fp32 acc.
// A tiles (64 rows) are staged global->reg->LDS with COALESCED global reads
// (fixes the 16-scattered-lines-per-instruction A-fragment pattern), stored
// XOR-swizzled (c16 ^= row&7) so fragment ds_reads are ~2-way conflict = free.
// B (Wt[128][KC]) register-resident per wave.

template<int KHALF>
__global__ __launch_bounds__(256)
void gemm_mfma(const u16* __restrict__ A1, const u16* __restrict__ A2,
               const u16* __restrict__ Wt, const float* __restrict__ bias,
               u16* __restrict__ out) {
    constexpr int KC    = 2 * KHALF;
    constexpr int NKS   = KC / 32;
    constexpr int RB    = KHALF * 2;       // bytes per A row (256 / 128)
    constexpr int C16   = RB / 16;         // 16B chunks per row (16 / 8)
    constexpr int TILEB = 64 * RB;         // bytes per A tile (16KB / 8KB)
    constexpr int ITER  = (TILEB / 16) / 256;  // chunks per thread (4 / 2)

    __shared__ __align__(16) char lds_t[2 * TILEB];

    int t = threadIdx.x;
    int lane = t & 63, w = t >> 6;
    int l15 = lane & 15, l4 = lane >> 4;
    int mbase = blockIdx.x * 64;

    // ---- stage A1, A2 into LDS (coalesced global reads, swizzled LDS writes) ----
    {
        const char* Ab0 = (const char*)(A1 + (size_t)mbase * KHALF);
        const char* Ab1 = (const char*)(A2 + (size_t)mbase * KHALF);
        #pragma unroll
        for (int tl = 0; tl < 2; tl++) {
            const char* Ab = tl ? Ab1 : Ab0;
            #pragma unroll
            for (int i = 0; i < ITER; i++) {
                int q = i * 256 + t;
                int row = q / C16;
                int c16 = q % C16;
                int c16s = c16 ^ (row & 7);
                uint4 v = make_uint4(0u, 0u, 0u, 0u);
                if (mbase + row < N_NODES)
                    v = *(const uint4*)(Ab + (size_t)row * RB + (size_t)c16 * 16);
                *(uint4*)&lds_t[tl * TILEB + row * RB + c16s * 16] = v;
            }
        }
    }

    // ---- B fragments: 2 col-tiles x NKS k-steps, register-resident ----
    bf16x8 bfr[2][NKS];
    #pragma unroll
    for (int ct = 0; ct < 2; ct++)
        #pragma unroll
        for (int ks = 0; ks < NKS; ks++) {
            int row = w * 32 + ct * 16 + l15;          // output col
            int kb  = ks * 32 + l4 * 8;
            bfr[ct][ks] = *reinterpret_cast<const bf16x8*>(Wt + row * KC + kb);
        }

    f32x4 acc[4][2];
    #pragma unroll
    for (int i = 0; i < 4; i++)
        #pragma unroll
        for (int j = 0; j < 2; j++)
            acc[i][j] = (f32x4){0.f, 0.f, 0.f, 0.f};

    __syncthreads();

    // ---- MFMA loop: A fragments from swizzled LDS ----
    #pragma unroll
    for (int ks = 0; ks < NKS; ks++) {
        int tl  = (ks < NKS / 2) ? 0 : 1;
        int ksl = (ks < NKS / 2) ? ks : (ks - NKS / 2);
        bf16x8 afr[4];
        #pragma unroll
        for (int rt = 0; rt < 4; rt++) {
            int rl = rt * 16 + l15;
            int c16 = ksl * 4 + l4;
            int c16s = c16 ^ (rl & 7);
            afr[rt] = *reinterpret_cast<const bf16x8*>(
                &lds_t[tl * TILEB + rl * RB + c16s * 16]);
        }
        #pragma unroll
        for (int rt = 0; rt < 4; rt++)
            #pragma unroll
            for (int ct = 0; ct < 2; ct++)
                acc[rt][ct] = __builtin_amdgcn_mfma_f32_16x16x32_bf16(
                    afr[rt], bfr[ct][ks], acc[rt][ct], 0, 0, 0);
    }

    // epilogue: bias + relu, store bf16. C/D: col=lane&15, row=(lane>>4)*4+reg
    #pragma unroll
    for (int ct = 0; ct < 2; ct++) {
        int col = w * 32 + ct * 16 + l15;
        float bv = bias[col];
        #pragma unroll
        for (int rt = 0; rt < 4; rt++) {
            #pragma unroll
            for (int j = 0; j < 4; j++) {
                int row = mbase + rt * 16 + l4 * 4 + j;
                if (row < N_NODES) {
                    float v = fmaxf(acc[rt][ct][j] + bv, 0.f);
                    out[(size_t)row * 128 + col] = f2b(v);
                }
            }
        }
    }
}

// ---------------- pooling (parallel partial sums) + LN/decode ----------------

__global__ __launch_bounds__(128)
void pool_partial(const u16* __restrict__ h, const int* __restrict__ batch,
                  float* __restrict__ gpool) {
    int c = threadIdx.x;
    int n0 = blockIdx.x * POOL_CHUNK;
    int n1 = n0 + POOL_CHUNK; if (n1 > N_NODES) n1 = N_NODES;
    float run = 0.f;
    int curg = -1;
    for (int r = n0; r < n1; r++) {
        int gid = batch[r];
        if (gid != curg) {
            if (curg >= 0) atomicAdd(&gpool[curg * 128 + c], run);
            run = 0.f; curg = gid;
        }
        run += b2f(h[(size_t)r * 128 + c]);
    }
    if (curg >= 0) atomicAdd(&gpool[curg * 128 + c], run);
}

__global__ __launch_bounds__(64)
void ln_decode(const float* __restrict__ gpool,
               const float* __restrict__ ln_g, const float* __restrict__ ln_b,
               const float* __restrict__ Wd, const float* __restrict__ bd,
               float* __restrict__ out) {
    int g = blockIdx.x, lane = threadIdx.x;
    float v0 = gpool[g * 128 + lane];
    float v1 = gpool[g * 128 + 64 + lane];
    float s = v0 + v1;
    #pragma unroll
    for (int off = 32; off > 0; off >>= 1) s += __shfl_xor(s, off, 64);
    float mu = s * (1.0f / 128.f);
    float d0 = v0 - mu, d1 = v1 - mu;
    float q = d0 * d0 + d1 * d1;
    #pragma unroll
    for (int off = 32; off > 0; off >>= 1) q += __shfl_xor(q, off, 64);
    float rs = rsqrtf(q * (1.0f / 128.f) + LN_EPS);
    float gn0 = d0 * rs * ln_g[lane]      + ln_b[lane];
    float gn1 = d1 * rs * ln_g[64 + lane] + ln_b[64 + lane];
    float o0 = gn0 * Wd[lane * 2 + 0] + gn1 * Wd[(64 + lane) * 2 + 0];
    float o1 = gn0 * Wd[lane * 2 + 1] + gn1 * Wd[(64 + lane) * 2 + 1];
    #pragma unroll
    for (int off = 32; off > 0; off >>= 1) {
        o0 += __shfl_xor(o0, off, 64);
        o1 += __shfl_xor(o1, off, 64);
    }
    if (lane == 0) {
        out[g * 2 + 0] = o0 + bd[0];
        out[g * 2 + 1] = o1 + bd[1];
    }
}

// ---------------- host launcher ----------------

extern "C" void kernel_launch(void* const* d_in, const int* in_sizes, int n_in,
                              void* d_out, int out_size, void* d_ws, size_t ws_size,
                              hipStream_t stream) {
    (void)in_sizes; (void)n_in; (void)out_size; (void)ws_size;

    const float* x     = (const float*)d_in[0];
    const int*   ei    = (const int*)d_in[1];
    const int*   batch = (const int*)d_in[2];
    const float* Wl0 = (const float*)d_in[3];
    const float* bl0 = (const float*)d_in[4];
    const float* Wr0 = (const float*)d_in[5];
    const float* Wl1 = (const float*)d_in[6];
    const float* bl1 = (const float*)d_in[7];
    const float* Wr1 = (const float*)d_in[8];
    const float* Wl2 = (const float*)d_in[9];
    const float* bl2 = (const float*)d_in[10];
    const float* Wr2 = (const float*)d_in[11];
    const float* ln_g = (const float*)d_in[12];
    const float* ln_b = (const float*)d_in[13];
    const float* Wd  = (const float*)d_in[14];
    const float* bd  = (const float*)d_in[15];
    float* out = (float*)d_out;

    const int* src = ei;
    const int* dst = ei + N_EDGES;

    // workspace layout (bytes)
    char* ws = (char*)d_ws;
    int*   csr     = (int*)(ws + 0);             //  6,400,000
    int*   offsets = (int*)(ws + 6400000);       //    400,128
    int*   bcnt    = (int*)(ws + 6800128);       //      1,024
    int*   bbase   = (int*)(ws + 6801152);       //      1,024
    uint2* bpool   = (uint2*)(ws + 6802176);     // 16,777,216
    u16*   x16     = (u16*)(ws + 23579392);      // 12,800,000
    u16*   aggbuf  = (u16*)(ws + 36379392);      // 25,600,000
    u16*   bufB    = (u16*)(ws + 61979392);      // 25,600,000
    u16*   bufC    = (u16*)(ws + 87579392);      // 25,600,000
    u16*   Wt0     = (u16*)(ws + 113179392);     //     32,768
    u16*   Wt1     = (u16*)(ws + 113212160);     //     65,536
    u16*   Wt2     = (u16*)(ws + 113277696);     //     65,536
    float* gpool   = (float*)(ws + 113343232);   //    262,144
    // total: 113,605,376 bytes

    hipMemsetAsync(bcnt, 0, NB * sizeof(int), stream);
    hipMemsetAsync(gpool, 0, N_GRAPHS * 128 * sizeof(float), stream);

    partition_edges<<<PBLOCKS, 256, 0, stream>>>(src, dst, bcnt, bpool);
    scan_buckets<<<1, 256, 0, stream>>>(bcnt, bbase, offsets);
    build_csr_bucket<<<NB, 256, 0, stream>>>(bcnt, bbase, bpool, offsets, csr);

    // conversions
    conv_f32_bf16<<<(N_NODES * 64 / 4 + 255) / 256, 256, 0, stream>>>(x, x16, N_NODES * 64 / 4);
    conv_weights<<<(128 * 128 + 255) / 256, 256, 0, stream>>>(Wl0, Wr0, 64, 128, Wt0);
    conv_weights<<<(128 * 256 + 255) / 256, 256, 0, stream>>>(Wl1, Wr1, 128, 256, Wt1);
    conv_weights<<<(128 * 256 + 255) / 256, 256, 0, stream>>>(Wl2, Wr2, 128, 256, Wt2);

    const int aggGrid  = N_NODES / 8;               // 12500 (exact)
    const int gemmGrid = (N_NODES + 63) / 64;       // 1563

    // layer 0
    aggregate_bf16<64><<<aggGrid, 256, 0, stream>>>(x16, offsets, csr, aggbuf);
    gemm_mfma<64><<<gemmGrid, 256, 0, stream>>>(aggbuf, x16, Wt0, bl0, bufB);
    // layer 1
    aggregate_bf16<128><<<aggGrid, 256, 0, stream>>>(bufB, offsets, csr, aggbuf);
    gemm_mfma<128><<<gemmGrid, 256, 0, stream>>>(aggbuf, bufB, Wt1, bl1, bufC);
    // layer 2
    aggregate_bf16<128><<<aggGrid, 256, 0, stream>>>(bufC, offsets, csr, aggbuf);
    gemm_mfma<128><<<gemmGrid, 256, 0, stream>>>(aggbuf, bufC, Wt2, bl2, bufB);

    // pool + LN + decode
    pool_partial<<<POOL_BLOCKS, 128, 0, stream>>>(bufB, batch, gpool);
    ln_decode<<<N_GRAPHS, 64, 0, stream>>>(gpool, ln_g, ln_b, Wd, bd, out);
}

// Round 10
// 340.553 us; speedup vs baseline: 2.2505x; 1.0012x over previous
//
#include <hip/hip_runtime.h>

#define N_NODES  100000
#define N_EDGES  1600000
#define N_GRAPHS 512
#define LN_EPS   1e-5f

#define NB    256          // dst buckets
#define NPB   391          // nodes per bucket (256*391 = 100096 >= N_NODES)
#define BCAP  8192         // pool capacity per bucket
#define PCHUNK 8192
#define PBLOCKS ((N_EDGES + PCHUNK - 1) / PCHUNK)   // 196
#define POOL_NPB 256
#define POOL_BLOCKS ((N_NODES + POOL_NPB - 1) / POOL_NPB)  // 391

typedef unsigned short u16;
typedef unsigned int   u32;
typedef __attribute__((ext_vector_type(8))) short bf16x8;
typedef __attribute__((ext_vector_type(4))) float f32x4;

__device__ __forceinline__ float b2f(u16 v) {
    u32 u = ((u32)v) << 16;
    return __builtin_bit_cast(float, u);
}
__device__ __forceinline__ u16 f2b(float f) {
    u32 u = __builtin_bit_cast(u32, f);
    u32 r = (u + 0x7fffu + ((u >> 16) & 1u)) >> 16;  // RNE
    return (u16)r;
}

// ---------------- init ----------------

__global__ void zero_init(int* __restrict__ bcnt, float* __restrict__ gpool) {
    int b = blockIdx.x, t = threadIdx.x;
    if (b < 256) gpool[b * 256 + t] = 0.f;   // 512*128 = 65536 = 256*256
    else bcnt[t] = 0;
}

// ---------------- bucketed CSR build ----------------
// Pass 1: bin edges into 256 dst-buckets; packed u32 entries (dl<<17 | src).

__global__ __launch_bounds__(256)
void partition_edges(const int* __restrict__ src, const int* __restrict__ dst,
                     int* __restrict__ bcnt, u32* __restrict__ bpool) {
    __shared__ int hist[NB];
    __shared__ int gbase[NB];
    __shared__ int cur[NB];
    int t = threadIdx.x;
    int e0 = blockIdx.x * PCHUNK;
    int e1 = e0 + PCHUNK; if (e1 > N_EDGES) e1 = N_EDGES;

    hist[t] = 0;
    __syncthreads();
    for (int e = e0 + t; e < e1; e += 256)
        atomicAdd(&hist[dst[e] / NPB], 1);
    __syncthreads();
    int h = hist[t];
    gbase[t] = (h > 0) ? atomicAdd(&bcnt[t], h) : 0;
    cur[t] = 0;
    __syncthreads();
    for (int e = e0 + t; e < e1; e += 256) {
        int d = dst[e], s = src[e];
        int bk = d / NPB;
        int p = atomicAdd(&cur[bk], 1);
        bpool[(size_t)bk * BCAP + gbase[bk] + p] =
            ((u32)(d - bk * NPB) << 17) | (u32)s;
    }
}

// Pass 2: per bucket. Prologue: 256-wide scan of bcnt -> own base (replaces
// the separate scan kernel). Then local hist + 512-scan -> offsets, LDS
// scatter, coalesced dump.
__global__ __launch_bounds__(256)
void build_csr_bucket(const int* __restrict__ bcnt, const u32* __restrict__ bpool,
                      int* __restrict__ offsets, int* __restrict__ csr) {
    __shared__ int sA[512];
    __shared__ int sB[512];
    __shared__ int csrL[BCAP];
    int b = blockIdx.x, t = threadIdx.x;

    // ---- bucket-base scan over bcnt[0..255] ----
    sA[t] = bcnt[t];
    __syncthreads();
    int* a = sA; int* c = sB;
    for (int off = 1; off < 256; off <<= 1) {
        c[t] = a[t] + ((t >= off) ? a[t - off] : 0);
        __syncthreads();
        int* tmp = a; a = c; c = tmp;
    }
    int count = bcnt[b];
    int base  = a[b] - count;                      // exclusive prefix
    if (b == NB - 1 && t == 0) offsets[N_NODES] = a[NB - 1];
    __syncthreads();

    int nlo = b * NPB;
    int NL = N_NODES - nlo; if (NL > NPB) NL = NPB;
    const u32* pool = bpool + (size_t)b * BCAP;

    // ---- local node histogram ----
    sA[t] = 0; sA[t + 256] = 0;
    __syncthreads();
    for (int i = t; i < count; i += 256)
        atomicAdd(&sA[(int)(pool[i] >> 17)], 1);
    __syncthreads();
    int c0 = sA[t], c1 = sA[t + 256];

    // ---- inclusive 512-scan (ping-pong) ----
    a = sA; c = sB;
    for (int off = 1; off < 512; off <<= 1) {
        c[t]       = a[t]       + ((t >= off)       ? a[t - off]       : 0);
        c[t + 256] = a[t + 256] + ((t + 256 >= off) ? a[t + 256 - off] : 0);
        __syncthreads();
        int* tmp = a; a = c; c = tmp;
    }
    int ex0 = a[t] - c0, ex1 = a[t + 256] - c1;    // exclusive
    if (t < NL)       offsets[nlo + t]       = base + ex0;
    if (t + 256 < NL) offsets[nlo + t + 256] = base + ex1;
    c[t] = ex0; c[t + 256] = ex1;                  // cursors in free buffer
    __syncthreads();
    for (int i = t; i < count; i += 256) {
        u32 p = pool[i];
        int pos = atomicAdd(&c[(int)(p >> 17)], 1);
        csrL[pos] = (int)(p & 0x1FFFFu);
    }
    __syncthreads();
    for (int i = t; i < count; i += 256)
        csr[base + i] = csrL[i];
}

// ---------------- fused conversions (x -> bf16, 3x weight transposes) ----------------

__global__ __launch_bounds__(256)
void conv_all(const float* __restrict__ x,
              const float* __restrict__ Wl0, const float* __restrict__ Wr0,
              const float* __restrict__ Wl1, const float* __restrict__ Wr1,
              const float* __restrict__ Wl2, const float* __restrict__ Wr2,
              u16* __restrict__ x16, u16* __restrict__ Wt0,
              u16* __restrict__ Wt1, u16* __restrict__ Wt2) {
    int b = blockIdx.x, t = threadIdx.x;
    if (b < 6250) {                              // 6250*256 = 1,600,000 float4s
        int i = b * 256 + t;
        float4 v = ((const float4*)x)[i];
        u32 lo = (u32)f2b(v.x) | ((u32)f2b(v.y) << 16);
        u32 hi = (u32)f2b(v.z) | ((u32)f2b(v.w) << 16);
        ((uint2*)x16)[i] = make_uint2(lo, hi);
    } else if (b < 6250 + 64) {                  // Wt0: 128x128
        int idx = (b - 6250) * 256 + t;
        int ch = idx / 128, k = idx % 128;
        float v = (k < 64) ? Wl0[k * 128 + ch] : Wr0[(k - 64) * 128 + ch];
        Wt0[idx] = f2b(v);
    } else if (b < 6250 + 64 + 128) {            // Wt1: 128x256
        int idx = (b - 6314) * 256 + t;
        int ch = idx / 256, k = idx % 256;
        float v = (k < 128) ? Wl1[k * 128 + ch] : Wr1[(k - 128) * 128 + ch];
        Wt1[idx] = f2b(v);
    } else {                                     // Wt2: 128x256
        int idx = (b - 6442) * 256 + t;
        int ch = idx / 256, k = idx % 256;
        float v = (k < 128) ? Wl2[k * 128 + ch] : Wr2[(k - 128) * 128 + ch];
        Wt2[idx] = f2b(v);
    }
}

// ---------------- mean aggregation (bf16 gather via CSR) ----------------
// 32 lanes per node, 8 nodes per 256-thr block, 4-way edge unroll.  (r6-verified;
// at compulsory L2-miss floor: FETCH ~ 8 XCD x buffer size @ ~3.4 TB/s)

template<int F>
__global__ __launch_bounds__(256)
void aggregate_bf16(const u16* __restrict__ in, const int* __restrict__ offsets,
                    const int* __restrict__ csr, u16* __restrict__ out) {
    int grp = threadIdx.x >> 5;
    int sub = threadIdx.x & 31;
    int n = blockIdx.x * 8 + grp;     // grid 12500 * 8 == N_NODES exactly
    int o0 = offsets[n], o1 = offsets[n + 1];
    int d = o1 - o0;
    float inv = 1.0f / (float)(d > 1 ? d : 1);

    if (F == 128) {
        const uint2* base = (const uint2*)in;      // row stride 32 uint2
        float acc[4][4];
        #pragma unroll
        for (int j = 0; j < 4; j++)
            #pragma unroll
            for (int c = 0; c < 4; c++) acc[j][c] = 0.f;

        int o = o0;
        for (; o + 4 <= o1; o += 4) {
            int s0 = csr[o + 0], s1 = csr[o + 1], s2 = csr[o + 2], s3 = csr[o + 3];
            uint2 v0 = base[(size_t)s0 * 32 + sub];
            uint2 v1 = base[(size_t)s1 * 32 + sub];
            uint2 v2 = base[(size_t)s2 * 32 + sub];
            uint2 v3 = base[(size_t)s3 * 32 + sub];
            acc[0][0] += b2f((u16)(v0.x & 0xffffu)); acc[0][1] += b2f((u16)(v0.x >> 16));
            acc[0][2] += b2f((u16)(v0.y & 0xffffu)); acc[0][3] += b2f((u16)(v0.y >> 16));
            acc[1][0] += b2f((u16)(v1.x & 0xffffu)); acc[1][1] += b2f((u16)(v1.x >> 16));
            acc[1][2] += b2f((u16)(v1.y & 0xffffu)); acc[1][3] += b2f((u16)(v1.y >> 16));
            acc[2][0] += b2f((u16)(v2.x & 0xffffu)); acc[2][1] += b2f((u16)(v2.x >> 16));
            acc[2][2] += b2f((u16)(v2.y & 0xffffu)); acc[2][3] += b2f((u16)(v2.y >> 16));
            acc[3][0] += b2f((u16)(v3.x & 0xffffu)); acc[3][1] += b2f((u16)(v3.x >> 16));
            acc[3][2] += b2f((u16)(v3.y & 0xffffu)); acc[3][3] += b2f((u16)(v3.y >> 16));
        }
        for (; o < o1; o++) {
            int s = csr[o];
            uint2 v = base[(size_t)s * 32 + sub];
            acc[0][0] += b2f((u16)(v.x & 0xffffu)); acc[0][1] += b2f((u16)(v.x >> 16));
            acc[0][2] += b2f((u16)(v.y & 0xffffu)); acc[0][3] += b2f((u16)(v.y >> 16));
        }
        float r0 = ((acc[0][0] + acc[1][0]) + (acc[2][0] + acc[3][0])) * inv;
        float r1 = ((acc[0][1] + acc[1][1]) + (acc[2][1] + acc[3][1])) * inv;
        float r2 = ((acc[0][2] + acc[1][2]) + (acc[2][2] + acc[3][2])) * inv;
        float r3 = ((acc[0][3] + acc[1][3]) + (acc[2][3] + acc[3][3])) * inv;
        uint2 w;
        w.x = (u32)f2b(r0) | ((u32)f2b(r1) << 16);
        w.y = (u32)f2b(r2) | ((u32)f2b(r3) << 16);
        ((uint2*)out)[(size_t)n * 32 + sub] = w;
    } else {
        const u32* base = (const u32*)in;          // row stride 32 u32
        float acc[4][2];
        #pragma unroll
        for (int j = 0; j < 4; j++) { acc[j][0] = 0.f; acc[j][1] = 0.f; }

        int o = o0;
        for (; o + 4 <= o1; o += 4) {
            int s0 = csr[o + 0], s1 = csr[o + 1], s2 = csr[o + 2], s3 = csr[o + 3];
            u32 v0 = base[(size_t)s0 * 32 + sub];
            u32 v1 = base[(size_t)s1 * 32 + sub];
            u32 v2 = base[(size_t)s2 * 32 + sub];
            u32 v3 = base[(size_t)s3 * 32 + sub];
            acc[0][0] += b2f((u16)(v0 & 0xffffu)); acc[0][1] += b2f((u16)(v0 >> 16));
            acc[1][0] += b2f((u16)(v1 & 0xffffu)); acc[1][1] += b2f((u16)(v1 >> 16));
            acc[2][0] += b2f((u16)(v2 & 0xffffu)); acc[2][1] += b2f((u16)(v2 >> 16));
            acc[3][0] += b2f((u16)(v3 & 0xffffu)); acc[3][1] += b2f((u16)(v3 >> 16));
        }
        for (; o < o1; o++) {
            int s = csr[o];
            u32 v = base[(size_t)s * 32 + sub];
            acc[0][0] += b2f((u16)(v & 0xffffu)); acc[0][1] += b2f((u16)(v >> 16));
        }
        float r0 = ((acc[0][0] + acc[1][0]) + (acc[2][0] + acc[3][0])) * inv;
        float r1 = ((acc[0][1] + acc[1][1]) + (acc[2][1] + acc[3][1])) * inv;
        ((u32*)out)[(size_t)n * 32 + sub] = (u32)f2b(r0) | ((u32)f2b(r1) << 16);
    }
}

// ---------------- fused dual GEMM via MFMA, LDS-staged A (r9-verified) ----------------

template<int KHALF>
__global__ __launch_bounds__(256)
void gemm_mfma(const u16* __restrict__ A1, const u16* __restrict__ A2,
               const u16* __restrict__ Wt, const float* __restrict__ bias,
               u16* __restrict__ out) {
    constexpr int KC    = 2 * KHALF;
    constexpr int NKS   = KC / 32;
    constexpr int RB    = KHALF * 2;       // bytes per A row (256 / 128)
    constexpr int C16   = RB / 16;         // 16B chunks per row (16 / 8)
    constexpr int TILEB = 64 * RB;         // bytes per A tile (16KB / 8KB)
    constexpr int ITER  = (TILEB / 16) / 256;  // chunks per thread (4 / 2)

    __shared__ __align__(16) char lds_t[2 * TILEB];

    int t = threadIdx.x;
    int lane = t & 63, w = t >> 6;
    int l15 = lane & 15, l4 = lane >> 4;
    int mbase = blockIdx.x * 64;

    // ---- stage A1, A2 into LDS (coalesced global reads, swizzled LDS writes) ----
    {
        const char* Ab0 = (const char*)(A1 + (size_t)mbase * KHALF);
        const char* Ab1 = (const char*)(A2 + (size_t)mbase * KHALF);
        #pragma unroll
        for (int tl = 0; tl < 2; tl++) {
            const char* Ab = tl ? Ab1 : Ab0;
            #pragma unroll
            for (int i = 0; i < ITER; i++) {
                int q = i * 256 + t;
                int row = q / C16;
                int c16 = q % C16;
                int c16s = c16 ^ (row & 7);
                uint4 v = make_uint4(0u, 0u, 0u, 0u);
                if (mbase + row < N_NODES)
                    v = *(const uint4*)(Ab + (size_t)row * RB + (size_t)c16 * 16);
                *(uint4*)&lds_t[tl * TILEB + row * RB + c16s * 16] = v;
            }
        }
    }

    // ---- B fragments: 2 col-tiles x NKS k-steps, register-resident ----
    bf16x8 bfr[2][NKS];
    #pragma unroll
    for (int ct = 0; ct < 2; ct++)
        #pragma unroll
        for (int ks = 0; ks < NKS; ks++) {
            int row = w * 32 + ct * 16 + l15;          // output col
            int kb  = ks * 32 + l4 * 8;
            bfr[ct][ks] = *reinterpret_cast<const bf16x8*>(Wt + row * KC + kb);
        }

    f32x4 acc[4][2];
    #pragma unroll
    for (int i = 0; i < 4; i++)
        #pragma unroll
        for (int j = 0; j < 2; j++)
            acc[i][j] = (f32x4){0.f, 0.f, 0.f, 0.f};

    __syncthreads();

    // ---- MFMA loop: A fragments from swizzled LDS ----
    #pragma unroll
    for (int ks = 0; ks < NKS; ks++) {
        int tl  = (ks < NKS / 2) ? 0 : 1;
        int ksl = (ks < NKS / 2) ? ks : (ks - NKS / 2);
        bf16x8 afr[4];
        #pragma unroll
        for (int rt = 0; rt < 4; rt++) {
            int rl = rt * 16 + l15;
            int c16 = ksl * 4 + l4;
            int c16s = c16 ^ (rl & 7);
            afr[rt] = *reinterpret_cast<const bf16x8*>(
                &lds_t[tl * TILEB + rl * RB + c16s * 16]);
        }
        #pragma unroll
        for (int rt = 0; rt < 4; rt++)
            #pragma unroll
            for (int ct = 0; ct < 2; ct++)
                acc[rt][ct] = __builtin_amdgcn_mfma_f32_16x16x32_bf16(
                    afr[rt], bfr[ct][ks], acc[rt][ct], 0, 0, 0);
    }

    // epilogue: bias + relu, store bf16. C/D: col=lane&15, row=(lane>>4)*4+reg
    #pragma unroll
    for (int ct = 0; ct < 2; ct++) {
        int col = w * 32 + ct * 16 + l15;
        float bv = bias[col];
        #pragma unroll
        for (int rt = 0; rt < 4; rt++) {
            #pragma unroll
            for (int j = 0; j < 4; j++) {
                int row = mbase + rt * 16 + l4 * 4 + j;
                if (row < N_NODES) {
                    float v = fmaxf(acc[rt][ct][j] + bv, 0.f);
                    out[(size_t)row * 128 + col] = f2b(v);
                }
            }
        }
    }
}

// ---------------- pooling (vectorized partial sums) + LN/decode ----------------
// 64 lanes per row (u32 = 2ch each), 4 row-groups per 256-thr block.

__global__ __launch_bounds__(256)
void pool_partial(const u16* __restrict__ h, const int* __restrict__ batch,
                  float* __restrict__ gpool) {
    int grp = threadIdx.x >> 6;
    int c   = threadIdx.x & 63;
    int n0 = blockIdx.x * POOL_NPB + grp * 64;
    int n1 = n0 + 64; if (n1 > N_NODES) n1 = N_NODES;
    const u32* h32 = (const u32*)h;
    float r0 = 0.f, r1 = 0.f;
    int curg = -1;
    for (int r = n0; r < n1; r++) {
        int gid = batch[r];
        if (gid != curg) {
            if (curg >= 0) {
                atomicAdd(&gpool[curg * 128 + c * 2 + 0], r0);
                atomicAdd(&gpool[curg * 128 + c * 2 + 1], r1);
            }
            r0 = 0.f; r1 = 0.f; curg = gid;
        }
        u32 v = h32[(size_t)r * 64 + c];
        r0 += b2f((u16)(v & 0xffffu));
        r1 += b2f((u16)(v >> 16));
    }
    if (curg >= 0) {
        atomicAdd(&gpool[curg * 128 + c * 2 + 0], r0);
        atomicAdd(&gpool[curg * 128 + c * 2 + 1], r1);
    }
}

__global__ __launch_bounds__(64)
void ln_decode(const float* __restrict__ gpool,
               const float* __restrict__ ln_g, const float* __restrict__ ln_b,
               const float* __restrict__ Wd, const float* __restrict__ bd,
               float* __restrict__ out) {
    int g = blockIdx.x, lane = threadIdx.x;
    float v0 = gpool[g * 128 + lane];
    float v1 = gpool[g * 128 + 64 + lane];
    float s = v0 + v1;
    #pragma unroll
    for (int off = 32; off > 0; off >>= 1) s += __shfl_xor(s, off, 64);
    float mu = s * (1.0f / 128.f);
    float d0 = v0 - mu, d1 = v1 - mu;
    float q = d0 * d0 + d1 * d1;
    #pragma unroll
    for (int off = 32; off > 0; off >>= 1) q += __shfl_xor(q, off, 64);
    float rs = rsqrtf(q * (1.0f / 128.f) + LN_EPS);
    float gn0 = d0 * rs * ln_g[lane]      + ln_b[lane];
    float gn1 = d1 * rs * ln_g[64 + lane] + ln_b[64 + lane];
    float o0 = gn0 * Wd[lane * 2 + 0] + gn1 * Wd[(64 + lane) * 2 + 0];
    float o1 = gn0 * Wd[lane * 2 + 1] + gn1 * Wd[(64 + lane) * 2 + 1];
    #pragma unroll
    for (int off = 32; off > 0; off >>= 1) {
        o0 += __shfl_xor(o0, off, 64);
        o1 += __shfl_xor(o1, off, 64);
    }
    if (lane == 0) {
        out[g * 2 + 0] = o0 + bd[0];
        out[g * 2 + 1] = o1 + bd[1];
    }
}

// ---------------- host launcher ----------------

extern "C" void kernel_launch(void* const* d_in, const int* in_sizes, int n_in,
                              void* d_out, int out_size, void* d_ws, size_t ws_size,
                              hipStream_t stream) {
    (void)in_sizes; (void)n_in; (void)out_size; (void)ws_size;

    const float* x     = (const float*)d_in[0];
    const int*   ei    = (const int*)d_in[1];
    const int*   batch = (const int*)d_in[2];
    const float* Wl0 = (const float*)d_in[3];
    const float* bl0 = (const float*)d_in[4];
    const float* Wr0 = (const float*)d_in[5];
    const float* Wl1 = (const float*)d_in[6];
    const float* bl1 = (const float*)d_in[7];
    const float* Wr1 = (const float*)d_in[8];
    const float* Wl2 = (const float*)d_in[9];
    const float* bl2 = (const float*)d_in[10];
    const float* Wr2 = (const float*)d_in[11];
    const float* ln_g = (const float*)d_in[12];
    const float* ln_b = (const float*)d_in[13];
    const float* Wd  = (const float*)d_in[14];
    const float* bd  = (const float*)d_in[15];
    float* out = (float*)d_out;

    const int* src = ei;
    const int* dst = ei + N_EDGES;

    // workspace layout (bytes)
    char* ws = (char*)d_ws;
    int*   csr     = (int*)(ws + 0);             //  6,400,000
    int*   offsets = (int*)(ws + 6400000);       //    400,128
    int*   bcnt    = (int*)(ws + 6800128);       //      1,024
    u32*   bpool   = (u32*)(ws + 6801152);       //  8,388,608 (256*8192*4)
    u16*   x16     = (u16*)(ws + 15189760);      // 12,800,000
    u16*   aggbuf  = (u16*)(ws + 27989760);      // 25,600,000
    u16*   bufB    = (u16*)(ws + 53589760);      // 25,600,000
    u16*   bufC    = (u16*)(ws + 79189760);      // 25,600,000
    u16*   Wt0     = (u16*)(ws + 104789760);     //     32,768
    u16*   Wt1     = (u16*)(ws + 104822528);     //     65,536
    u16*   Wt2     = (u16*)(ws + 104888064);     //     65,536
    float* gpool   = (float*)(ws + 104953600);   //    262,144
    // total: 105,215,744 bytes

    zero_init<<<257, 256, 0, stream>>>(bcnt, gpool);
    partition_edges<<<PBLOCKS, 256, 0, stream>>>(src, dst, bcnt, bpool);
    build_csr_bucket<<<NB, 256, 0, stream>>>(bcnt, bpool, offsets, csr);
    conv_all<<<6570, 256, 0, stream>>>(x, Wl0, Wr0, Wl1, Wr1, Wl2, Wr2,
                                       x16, Wt0, Wt1, Wt2);

    const int aggGrid  = N_NODES / 8;               // 12500 (exact)
    const int gemmGrid = (N_NODES + 63) / 64;       // 1563

    // layer 0
    aggregate_bf16<64><<<aggGrid, 256, 0, stream>>>(x16, offsets, csr, aggbuf);
    gemm_mfma<64><<<gemmGrid, 256, 0, stream>>>(aggbuf, x16, Wt0, bl0, bufB);
    // layer 1
    aggregate_bf16<128><<<aggGrid, 256, 0, stream>>>(bufB, offsets, csr, aggbuf);
    gemm_mfma<128><<<gemmGrid, 256, 0, stream>>>(aggbuf, bufB, Wt1, bl1, bufC);
    // layer 2
    aggregate_bf16<128><<<aggGrid, 256, 0, stream>>>(bufC, offsets, csr, aggbuf);
    gemm_mfma<128><<<gemmGrid, 256, 0, stream>>>(aggbuf, bufC, Wt2, bl2, bufB);

    // pool + LN + decode
    pool_partial<<<POOL_BLOCKS, 256, 0, stream>>>(bufB, batch, gpool);
    ln_decode<<<N_GRAPHS, 64, 0, stream>>>(gpool, ln_g, ln_b, Wd, bd, out);
}